// Round 3
// baseline (107.372 us; speedup 1.0000x reference)
//
#include <hip/hip_runtime.h>
#include <math.h>

#define BB 65536
#define DD 256
#define KK 10
#define LOG_2PI 1.8378770664093453f

__device__ __forceinline__ float rl(float v, int lane) {
    return __int_as_float(__builtin_amdgcn_readlane(__float_as_int(v), lane));
}

// ---------------------------------------------------------------------------
// Fully fused single kernel, spill-safe. Round-1's fused attempt regressed
// because __launch_bounds__(256,4) capped VGPR at 128 and the unrolled
// prologue spilled ~52 MB to scratch (WRITE_SIZE 57.8 MB vs 5.5 MB real,
// VGPR_Count 52). Fix: plain __launch_bounds__(256) — LDS (69.8 KB) already
// pins occupancy at 2 blocks/CU, so each wave gets ~256 VGPRs.
//
// Structure = round-2 main (R=2 rows/lane, verified) + in-register w build
// (verbatim from round 1, verified) + barrier-free per-wave C partials.
// Wave c owns dim-chunk c; lane r owns rows r and r+64. All arithmetic
// (w slots, accumulation order, shfl chain, C association, epilogue) is
// bit-identical to the two-kernel version.
// grid = B/128 = 512 blocks; LDS 69.8 KB -> 2 blocks/CU (one pass).
// ---------------------------------------------------------------------------
__global__ __launch_bounds__(256) void gmvae_fused(
    const float* __restrict__ q_z,
    const float* __restrict__ mu_table,
    const float* __restrict__ logvar_table,
    float* __restrict__ out)
{
    __shared__ float4 buf[2 * 128 * 17];           // 69.6 KB, row stride 17
    __shared__ float red[KK * 4];                  // per-wave C partials
    float* comb = reinterpret_cast<float*>(buf);   // aliased in epilogue

    const int t    = threadIdx.x;
    const int r    = t & 63;                                   // lane
    const int c    = __builtin_amdgcn_readfirstlane(t >> 6);   // wave id
    const int row0 = blockIdx.x * 128;

    const float4* __restrict__ q4 = reinterpret_cast<const float4*>(q_z);

    // thread's staging slice: 8 f4 per stage (128 rows x 16 f4 / 256 thr)
    const int rr0 = t >> 4;
    const int ff  = t & 15;

    // ---- issue stage-0 q loads FIRST; prologue below hides their latency
    float4 v[8];
    #pragma unroll
    for (int i = 0; i < 8; ++i)
        v[i] = q4[(size_t)(row0 + i * 16 + rr0) * 64 + 0 * 16 + ff];

    // ---- in-register coefficient slice build (inverts prep's tab layout):
    // slot p = i*64+r -> half=r&1 (even: iv, odd: -2*mu*iv), q=i*32+(r>>1),
    // k=q%10, sj=q/10, f=(sj>>2)*16 + c*4 + (sj&3). Verified in round 1.
    const float4* __restrict__ mu4 = reinterpret_cast<const float4*>(mu_table);
    const float4* __restrict__ lv4 = reinterpret_cast<const float4*>(logvar_table);
    const int odd = r & 1;
    float4 w[5];
    #pragma unroll
    for (int i = 0; i < 5; ++i) {
        const int qq = i * 32 + (r >> 1);          // slot pair index 0..159
        const int k  = qq % KK;
        const int sj = qq / KK;                    // s*4 + jj, 0..15
        const int f  = (sj >> 2) * 16 + c * 4 + (sj & 3);   // global f4 0..63
        const float4 lv = lv4[k * 64 + f];
        const float4 m  = mu4[k * 64 + f];
        const float iv0 = expf(-lv.x), iv1 = expf(-lv.y);
        const float iv2 = expf(-lv.z), iv3 = expf(-lv.w);
        if (odd) {      // na = -2 * (m * iv), same association as prep
            const float a0 = m.x * iv0, a1 = m.y * iv1;
            const float a2 = m.z * iv2, a3 = m.w * iv3;
            w[i] = make_float4(-2.0f * a0, -2.0f * a1, -2.0f * a2, -2.0f * a3);
        } else {
            w[i] = make_float4(iv0, iv1, iv2, iv3);
        }
    }

    // ---- barrier-free C partials: wave c reduces dims [c*64, c*64+64) per k
    // (identical partition + shfl chain as the old prep kernel). No sync
    // needed here — the pipeline's barriers below make red[] visible before
    // the epilogue reads it.
    #pragma unroll
    for (int k = 0; k < KK; ++k) {
        const float lvv = logvar_table[k * DD + c * 64 + r];
        const float m   = mu_table[k * DD + c * 64 + r];
        const float iv  = expf(-lvv);
        const float a   = m * iv;
        float p = fmaf(m, a, lvv);                 // mu^2*iv + lv
        #pragma unroll
        for (int off = 32; off > 0; off >>= 1)
            p += __shfl_down(p, off, 64);
        if (r == 0)
            red[k * 4 + c] = p;
    }

    float accA[KK], accB[KK];
    #pragma unroll
    for (int k = 0; k < KK; ++k) { accA[k] = 0.f; accB[k] = 0.f; }

    // ---- stage 0 into LDS
    #pragma unroll
    for (int i = 0; i < 8; ++i)
        buf[(i * 16 + rr0) * 17 + ff] = v[i];
    __syncthreads();

    #pragma unroll
    for (int s = 0; s < 4; ++s) {
        // issue next stage's global loads (hide under compute)
        if (s < 3) {
            #pragma unroll
            for (int i = 0; i < 8; ++i)
                v[i] = q4[(size_t)(row0 + i * 16 + rr0) * 64 + (s + 1) * 16 + ff];
        }

        // compute stage s from LDS buf[s&1]; coefficients via readlane,
        // each broadcast reused for both rows (r and r+64)
        const float4* bpA = buf + (s & 1) * (128 * 17) + r * 17 + c * 4;
        const float4* bpB = bpA + 64 * 17;
        #pragma unroll
        for (int jj = 0; jj < 4; ++jj) {
            const float4 qa = bpA[jj];
            const float4 qb = bpB[jj];
            const float ax2 = qa.x * qa.x, ay2 = qa.y * qa.y;
            const float az2 = qa.z * qa.z, aw2 = qa.w * qa.w;
            const float bx2 = qb.x * qb.x, by2 = qb.y * qb.y;
            const float bz2 = qb.z * qb.z, bw2 = qb.w * qb.w;
            #pragma unroll
            for (int k = 0; k < KK; ++k) {
                const int flat = ((s * 4 + jj) * KK + k) * 2;  // iv f4 slot
                const int i = flat >> 6;
                const int L = flat & 63;                       // na at L+1
                const float4 wv = w[i];
                const float ivx = rl(wv.x, L), nax = rl(wv.x, L + 1);
                const float ivy = rl(wv.y, L), nay = rl(wv.y, L + 1);
                const float ivz = rl(wv.z, L), naz = rl(wv.z, L + 1);
                const float ivw = rl(wv.w, L), naw = rl(wv.w, L + 1);
                accA[k] = fmaf(ax2, ivx, accA[k]);
                accA[k] = fmaf(qa.x, nax, accA[k]);
                accA[k] = fmaf(ay2, ivy, accA[k]);
                accA[k] = fmaf(qa.y, nay, accA[k]);
                accA[k] = fmaf(az2, ivz, accA[k]);
                accA[k] = fmaf(qa.z, naz, accA[k]);
                accA[k] = fmaf(aw2, ivw, accA[k]);
                accA[k] = fmaf(qa.w, naw, accA[k]);
                accB[k] = fmaf(bx2, ivx, accB[k]);
                accB[k] = fmaf(qb.x, nax, accB[k]);
                accB[k] = fmaf(by2, ivy, accB[k]);
                accB[k] = fmaf(qb.y, nay, accB[k]);
                accB[k] = fmaf(bz2, ivz, accB[k]);
                accB[k] = fmaf(qb.z, naz, accB[k]);
                accB[k] = fmaf(bw2, ivw, accB[k]);
                accB[k] = fmaf(qb.w, naw, accB[k]);
            }
        }

        // stage s+1 into the other buffer, one barrier per stage
        if (s < 3) {
            float4* wp = buf + ((s + 1) & 1) * (128 * 17);
            #pragma unroll
            for (int i = 0; i < 8; ++i)
                wp[(i * 16 + rr0) * 17 + ff] = v[i];
            __syncthreads();
        }
    }

    // cross-wave combine: rows 0-63 from accA at comb[t], rows 64-127 from
    // accB at comb[256+t] (stride 11, odd -> conflict-free)
    __syncthreads();                   // all LDS q reads done; safe to alias
    #pragma unroll
    for (int k = 0; k < KK; ++k) {
        comb[t * 11 + k]         = accA[k];
        comb[(256 + t) * 11 + k] = accB[k];
    }
    __syncthreads();                   // also makes red[] visible

    if (t < 128) {                     // waves 0-1 epilogue: row = row0 + t
        const int hb = t >> 6;         // 0: accA rows, 1: accB rows
        const int rr = t & 63;
        const int cb = hb * 256 + rr;
        float l[KK];
        #pragma unroll
        for (int k = 0; k < KK; ++k) {
            const float vsum =
                ((comb[cb * 11 + k]         + comb[(cb + 64) * 11 + k]) +
                 (comb[(cb + 128) * 11 + k] + comb[(cb + 192) * 11 + k]));
            // C[k]: bit-identical to the old prep kernel's formula
            const float s2 = (red[k * 4 + 0] + red[k * 4 + 1]) +
                             (red[k * 4 + 2] + red[k * 4 + 3]);
            const float Ck = -0.5f * (s2 + 256.0f * LOG_2PI) + logf(0.1f);
            l[k] = fmaf(vsum, -0.5f, Ck);
        }

        float mx = l[0];
        #pragma unroll
        for (int k = 1; k < KK; ++k) mx = fmaxf(mx, l[k]);

        float e[KK];
        float sum = 0.f;
        #pragma unroll
        for (int k = 0; k < KK; ++k) { e[k] = __expf(l[k] - mx); sum += e[k]; }
        const float inv = 1.0f / sum;

        int idx = 0;
        float best = l[0];
        #pragma unroll
        for (int k = 1; k < KK; ++k)
            if (l[k] > best) { best = l[k]; idx = k; }

        const int row = row0 + t;
        float2* __restrict__ o1 =
            reinterpret_cast<float2*>(out) + (size_t)row * 5;
        float2* __restrict__ o2 =
            reinterpret_cast<float2*>(out + (size_t)BB * KK) + (size_t)row * 5;
        #pragma unroll
        for (int k = 0; k < 5; ++k)
            o1[k] = make_float2(l[2 * k], l[2 * k + 1]);
        #pragma unroll
        for (int k = 0; k < 5; ++k)
            o2[k] = make_float2(e[2 * k] * inv, e[2 * k + 1] * inv);
        out[(size_t)2 * BB * KK + row] = (float)idx;
    }
}

extern "C" void kernel_launch(void* const* d_in, const int* in_sizes, int n_in,
                              void* d_out, int out_size, void* d_ws, size_t ws_size,
                              hipStream_t stream) {
    const float* q_z    = (const float*)d_in[0];
    const float* mu     = (const float*)d_in[1];
    const float* logvar = (const float*)d_in[2];
    (void)d_ws; (void)ws_size;          // workspace deliberately untouched
    gmvae_fused<<<BB / 128, 256, 0, stream>>>(q_z, mu, logvar, (float*)d_out);
}